// Round 9
// baseline (228.241 us; speedup 1.0000x reference)
//
#include <hip/hip_runtime.h>
#include <hip/hip_bf16.h>
#include <cmath>

typedef __hip_bfloat16 bf16;
typedef short v8s __attribute__((ext_vector_type(8)));   // 8 x bf16 bits
typedef short v4s __attribute__((ext_vector_type(4)));   // 4 x bf16 bits
typedef float v4f __attribute__((ext_vector_type(4)));

#define AS1(p) ((__attribute__((address_space(1))) void*)(p))
#define AS3(p) ((__attribute__((address_space(3))) void*)(p))

__device__ __forceinline__ v4f mfma_bf16(v8s a, v8s b, v4f c) {
    return __builtin_amdgcn_mfma_f32_16x16x32_bf16(a, b, c, 0, 0, 0);
}

__device__ __forceinline__ short bf16_bits(float f) {
    return __builtin_bit_cast(short, __float2bfloat16(f));
}

// fused fp32 -> bf16 for x, w_in, w_out (float4 granularity)
__global__ __launch_bounds__(256)
void cvt_all(const float* __restrict__ x, const float* __restrict__ w_in,
             const float* __restrict__ w_out, bf16* __restrict__ xb,
             bf16* __restrict__ wib, bf16* __restrict__ wob)
{
    const int i = blockIdx.x * 256 + threadIdx.x;   // 0 .. 2097151
    const float* src; bf16* dst; int j;
    if (i < 1048576)      { src = x;     dst = xb;  j = i; }
    else if (i < 1835008) { src = w_in;  dst = wib; j = i - 1048576; }
    else                  { src = w_out; dst = wob; j = i - 1835008; }
    const float4 v = ((const float4*)src)[j];
    v4s p;
    p.x = bf16_bits(v.x); p.y = bf16_bits(v.y);
    p.z = bf16_bits(v.z); p.w = bf16_bits(v.w);
    ((v4s*)dst)[j] = p;
}

// C[m,n] = sum_k A[m,k] * Bt[n,k] + bias[n].  Tile: 128 x (NF*32), BK=32,
// double-buffered (stage k+1 right after the single per-iter barrier).
// XOR-4 swizzled 64B LDS rows (store chunk (t&3)^((row>>1)&3), read
// quad^((l16>>1)&3)) - conflict-free. Output: cols >= 2048 scatter to
// Vt[bh][d][s] (measured-free vs coalesced store: r5/r6 A/B); else store at
// ldc stride: Cf (fp32) if non-null, else C (bf16).
template<int NF>
__global__ __launch_bounds__(256)
void gemm_bt(const bf16* __restrict__ A, const bf16* __restrict__ Bt,
             const float* __restrict__ bias, bf16* __restrict__ C,
             float* __restrict__ Cf, bf16* __restrict__ Vt,
             int K, int lda, int ldc)
{
    constexpr int BN = NF * 32;
    __shared__ __align__(16) bf16 As[2][128 * 32];
    __shared__ __align__(16) bf16 Bs[2][BN * 32];

    const int t    = threadIdx.x;
    const int lane = t & 63;
    const int wave = t >> 6;
    const int l16  = lane & 15;
    const int quad = lane >> 4;
    const int m0   = blockIdx.y * 128;
    const int n0   = blockIdx.x * BN;
    const int wm   = (wave >> 1) * 64;        // 2x2 wave grid
    const int wn   = (wave & 1) * (NF * 16);

    const v4f zf = {0.f, 0.f, 0.f, 0.f};
    v4f acc[4][NF];
#pragma unroll
    for (int i = 0; i < 4; ++i)
#pragma unroll
        for (int j = 0; j < NF; ++j) acc[i][j] = zf;

    const int sr = t >> 2;
    const int g  = ((t & 3) ^ ((sr >> 1) & 3)) * 8;
    const bf16* gA = A  + (size_t)(m0 + sr) * lda + g;
    const bf16* gB = Bt + (size_t)(n0 + sr) * K + g;

    auto stage = [&](int kt, int buf) {
        const int k0 = kt * 32;
        char* lA = (char*)&As[buf][0] + t * 16;
        char* lB = (char*)&Bs[buf][0] + t * 16;
        __builtin_amdgcn_global_load_lds(AS1(gA + k0),                    AS3(lA),        16, 0, 0);
        __builtin_amdgcn_global_load_lds(AS1(gA + (size_t)64 * lda + k0), AS3(lA + 4096), 16, 0, 0);
        __builtin_amdgcn_global_load_lds(AS1(gB + k0),                    AS3(lB),        16, 0, 0);
        if (NF == 4)
            __builtin_amdgcn_global_load_lds(AS1(gB + (size_t)64 * K + k0), AS3(lB + 4096), 16, 0, 0);
    };

    stage(0, 0);
    const int KT = K >> 5;
    const int xs = ((l16 >> 1) & 3) * 8;   // read-side chunk swizzle
    for (int kt = 0; kt < KT; ++kt) {
        const int buf = kt & 1;
        __syncthreads();                    // buf staged; prev reads of buf^1 done
        if (kt + 1 < KT) stage(kt + 1, buf ^ 1);

        v8s af[4], bfr[NF];
#pragma unroll
        for (int mi = 0; mi < 4; ++mi)
            af[mi] = *(const v8s*)(&As[buf][0] + (wm + mi * 16 + l16) * 32
                                   + ((quad * 8) ^ xs));
#pragma unroll
        for (int ni = 0; ni < NF; ++ni)
            bfr[ni] = *(const v8s*)(&Bs[buf][0] + (wn + ni * 16 + l16) * 32
                                    + ((quad * 8) ^ xs));
#pragma unroll
        for (int mi = 0; mi < 4; ++mi)
#pragma unroll
            for (int ni = 0; ni < NF; ++ni)
                acc[mi][ni] = mfma_bf16(af[mi], bfr[ni], acc[mi][ni]);
    }

    // epilogue: D[row=quad*4+r][col=l16] per 16x16 tile (m91-verified layout)
#pragma unroll
    for (int ni = 0; ni < NF; ++ni) {
        const int col = n0 + wn + ni * 16 + l16;
        const float bv = bias[col];
#pragma unroll
        for (int mi = 0; mi < 4; ++mi) {
#pragma unroll
            for (int r = 0; r < 4; ++r) {
                const int row = m0 + wm + mi * 16 + quad * 4 + r;
                const float fv = acc[mi][ni][r] + bv;
                if (Vt && col >= 2048) {          // V third -> Vt[bh][d][s]
                    const int e = col - 2048;
                    const int hh = e >> 6, d = e & 63;
                    const int bb = row >> 11, s = row & 2047;
                    Vt[((((size_t)(bb * 16 + hh)) * 64 + d) << 11) + s] = __float2bfloat16(fv);
                } else if (Cf) {
                    Cf[(size_t)row * ldc + col] = fv;
                } else {
                    C[(size_t)row * ldc + col] = __float2bfloat16(fv);
                }
            }
        }
    }
}

// Block-cooperative causal flash attention, 64 q-rows/block (16/wave).
// qkv: [4096][2048] (Q cols 0..1023, K cols 1024..2047). Vt: [32*64][2048].
// att out: dense [4096][1024]. K tiles (64) double-buffered in LDS via
// global_load_lds prefetch, ONE __syncthreads per tile. V fragments read
// DIRECTLY from global Vt (L2-resident, ~256KB/head) - no Vs staging ->
// LDS 25.6KB -> ~5 blocks/CU. V loads issued at tile top, consumed after exp.
// Static-max softmax p = exp(s/8 - 14): no per-tile reductions/rescale.
#define M_STATIC 14.0f
__global__ __launch_bounds__(256)
void attn(const bf16* __restrict__ qkv, const bf16* __restrict__ Vt,
          bf16* __restrict__ att)
{
    __shared__ __align__(16) bf16 Ks[2][64 * 64];   // [krow][d-chunk swizzled]
    __shared__ __align__(16) short Ps[4][16 * 72];  // per-wave P, stride 72 (pad)

    const int t    = threadIdx.x;
    const int lane = t & 63;
    const int w    = t >> 6;
    const int l16  = lane & 15;
    const int quad = lane >> 4;
    const int id   = blockIdx.x;          // 1024 blocks
    const int bh   = id & 31;
    const int qb   = 31 - (id >> 5);      // heavy-first: qb 31..0
    const int b = bh >> 4, h = bh & 15;
    const int T = qb + 1;                 // 64-wide k-tiles to the causal frontier
    const int rowq = qb * 64 + w * 16;    // wave's first q-row

    // Q fragments (A-layout), 16 rows per wave
    v8s qf[2];
    {
        const bf16* Qb = qkv + (size_t)(b * 2048 + rowq + l16) * 2048 + h * 64 + quad * 8;
        qf[0] = *(const v8s*)(Qb);
        qf[1] = *(const v8s*)(Qb + 32);
    }

    // K staging: thread t fetches 16B; LDS dst = t*16; global chunk = sc^(sr&7)
    const int sr  = t >> 3;          // row 0..31 within half-tile
    const int swz = ((t & 7) ^ (sr & 7)) * 8;
    const bf16* kbase = qkv + (size_t)(b * 2048 + sr) * 2048 + 1024 + h * 64 + swz;
    char* kd = (char*)&Ks[0][0] + t * 16;

    // V row pointers for direct-from-global fragments
    const bf16* vrow[4];
#pragma unroll
    for (int nt = 0; nt < 4; ++nt)
        vrow[nt] = Vt + (size_t)(bh * 64 + nt * 16 + l16) * 2048 + quad * 8;

    // stage K tile 0 into buf 0
    __builtin_amdgcn_global_load_lds(AS1(kbase),                     AS3(kd),        16, 0, 0);
    __builtin_amdgcn_global_load_lds(AS1(kbase + (size_t)32 * 2048), AS3(kd + 4096), 16, 0, 0);

    const v4f zf = {0.f, 0.f, 0.f, 0.f};
    v4f o[4] = {zf, zf, zf, zf};
    float lsum[4] = {0.f, 0.f, 0.f, 0.f};
    short* Pw = &Ps[w][0];
    const int xsw = (l16 & 7) * 8;   // fragment-read swizzle (chunk' = c ^ (l16&7))

    for (int tile = 0; tile < T; ++tile) {
        const int buf = tile & 1;
        __syncthreads();   // K tile staged; all prior reads of buf^1 done
        if (tile + 1 < T) {          // prefetch next K tile
            const bf16* ksrc = kbase + (size_t)((tile + 1) * 64) * 2048;
            char* kdn = (char*)&Ks[buf ^ 1][0] + t * 16;
            __builtin_amdgcn_global_load_lds(AS1(ksrc),                     AS3(kdn),        16, 0, 0);
            __builtin_amdgcn_global_load_lds(AS1(ksrc + (size_t)32 * 2048), AS3(kdn + 4096), 16, 0, 0);
        }

        // V fragments for this tile: issue early, consume after exp
        v8s vfr[2][4];
#pragma unroll
        for (int ks = 0; ks < 2; ++ks)
#pragma unroll
            for (int nt = 0; nt < 4; ++nt)
                vfr[ks][nt] = *(const v8s*)(vrow[nt] + tile * 64 + ks * 32);

        // QK^T: S[16 rows][64 cols]
        v4f s[4] = {zf, zf, zf, zf};
#pragma unroll
        for (int ks = 0; ks < 2; ++ks)
#pragma unroll
            for (int ct = 0; ct < 4; ++ct) {
                const v8s kf = *(const v8s*)(&Ks[buf][0] + (ct * 16 + l16) * 64
                                             + (((ks * 4 + quad) * 8) ^ xsw));
                s[ct] = mfma_bf16(qf[ks], kf, s[ct]);
            }

        // exp (static max); mask only on the diagonal tile (wave-uniform branch)
        if (tile == T - 1) {
            const int colb = tile * 64;
            const int rowb = rowq + quad * 4;
#pragma unroll
            for (int ct = 0; ct < 4; ++ct) {
                const int col = colb + ct * 16 + l16;
#pragma unroll
                for (int r = 0; r < 4; ++r) {
                    const float p = (col > rowb + r)
                        ? 0.f : __expf(fmaf(s[ct][r], 0.125f, -M_STATIC));
                    lsum[r] += p;
                    Pw[(quad * 4 + r) * 72 + ct * 16 + l16] = bf16_bits(p);
                }
            }
        } else {
#pragma unroll
            for (int ct = 0; ct < 4; ++ct)
#pragma unroll
                for (int r = 0; r < 4; ++r) {
                    const float p = __expf(fmaf(s[ct][r], 0.125f, -M_STATIC));
                    lsum[r] += p;
                    Pw[(quad * 4 + r) * 72 + ct * 16 + l16] = bf16_bits(p);
                }
        }
        // per-wave P write->read ordering WITHOUT draining vmcnt (prefetch lives)
        asm volatile("s_waitcnt lgkmcnt(0)" ::: "memory");

        // PV: O += P[16x64] * V[64x64]   (V frags from global, already in flight)
#pragma unroll
        for (int ks = 0; ks < 2; ++ks) {
            const v8s pf = *(const v8s*)(Pw + l16 * 72 + ks * 32 + quad * 8);
#pragma unroll
            for (int nt = 0; nt < 4; ++nt)
                o[nt] = mfma_bf16(pf, vfr[ks][nt], o[nt]);
        }
    }

    // row-sum: reduce partials across the 16 lanes holding each row (once)
#pragma unroll
    for (int r = 0; r < 4; ++r) {
        float l = lsum[r];
        l += __shfl_xor(l, 1); l += __shfl_xor(l, 2);
        l += __shfl_xor(l, 4); l += __shfl_xor(l, 8);
        lsum[r] = fmaxf(l, 1e-30f);
    }

    // dense attention output [4096][1024]
#pragma unroll
    for (int nt = 0; nt < 4; ++nt)
#pragma unroll
        for (int r = 0; r < 4; ++r) {
            const int row = rowq + quad * 4 + r;
            att[(size_t)(b * 2048 + row) * 1024 + h * 64 + nt * 16 + l16] =
                __float2bfloat16(o[nt][r] / lsum[r]);
        }
}

extern "C" void kernel_launch(void* const* d_in, const int* in_sizes, int n_in,
                              void* d_out, int out_size, void* d_ws, size_t ws_size,
                              hipStream_t stream)
{
    (void)in_sizes; (void)n_in; (void)out_size; (void)ws_size;
    const float* x     = (const float*)d_in[0];
    const float* w_in  = (const float*)d_in[1];
    const float* b_in  = (const float*)d_in[2];
    const float* w_out = (const float*)d_in[3];
    const float* b_out = (const float*)d_in[4];
    float* out = (float*)d_out;   // fp32 output [4096][1024]

    bf16* ws     = (bf16*)d_ws;
    bf16* xb     = ws;                           // [4096][1024]   8.4 MB
    bf16* w_inb  = xb     + (size_t)4096 * 1024; // [3072][1024]   6.3 MB
    bf16* w_outb = w_inb  + (size_t)3072 * 1024; // [1024][1024]   2.1 MB
    bf16* qkv    = w_outb + (size_t)1024 * 1024; // [4096][2048]  16.8 MB (Q,K)
    bf16* att    = qkv    + (size_t)4096 * 2048; // [4096][1024]   8.4 MB
    bf16* vt     = (bf16*)d_out;                 // [32*64][2048] scratch in d_out
                                                 // (dead before final GEMM writes out)

    cvt_all<<<8192, 256, 0, stream>>>(x, w_in, w_out, xb, w_inb, w_outb);

    // QKV projection: Q,K -> qkv (stride 2048); V scattered direct to Vt
    gemm_bt<4><<<dim3(24, 32), dim3(256), 0, stream>>>(xb, w_inb, b_in, qkv, nullptr,
                                                       vt, 1024, 1024, 2048);
    // causal flash attention -> dense att
    attn<<<1024, 256, 0, stream>>>(qkv, vt, att);
    // output projection -> fp32 d_out
    gemm_bt<2><<<dim3(16, 32), dim3(256), 0, stream>>>(att, w_outb, b_out, nullptr,
                                                       out, nullptr, 1024, 1024, 1024);
}

// Round 10
// 189.080 us; speedup vs baseline: 1.2071x; 1.2071x over previous
//
#include <hip/hip_runtime.h>
#include <hip/hip_bf16.h>
#include <cmath>

typedef __hip_bfloat16 bf16;
typedef short v8s __attribute__((ext_vector_type(8)));   // 8 x bf16 bits
typedef short v4s __attribute__((ext_vector_type(4)));   // 4 x bf16 bits
typedef float v4f __attribute__((ext_vector_type(4)));

#define AS1(p) ((__attribute__((address_space(1))) void*)(p))
#define AS3(p) ((__attribute__((address_space(3))) void*)(p))

__device__ __forceinline__ v4f mfma_bf16(v8s a, v8s b, v4f c) {
    return __builtin_amdgcn_mfma_f32_16x16x32_bf16(a, b, c, 0, 0, 0);
}

__device__ __forceinline__ short bf16_bits(float f) {
    return __builtin_bit_cast(short, __float2bfloat16(f));
}

// fused fp32 -> bf16 for x, w_in, w_out (float4 granularity)
__global__ __launch_bounds__(256)
void cvt_all(const float* __restrict__ x, const float* __restrict__ w_in,
             const float* __restrict__ w_out, bf16* __restrict__ xb,
             bf16* __restrict__ wib, bf16* __restrict__ wob)
{
    const int i = blockIdx.x * 256 + threadIdx.x;   // 0 .. 2097151
    const float* src; bf16* dst; int j;
    if (i < 1048576)      { src = x;     dst = xb;  j = i; }
    else if (i < 1835008) { src = w_in;  dst = wib; j = i - 1048576; }
    else                  { src = w_out; dst = wob; j = i - 1835008; }
    const float4 v = ((const float4*)src)[j];
    v4s p;
    p.x = bf16_bits(v.x); p.y = bf16_bits(v.y);
    p.z = bf16_bits(v.z); p.w = bf16_bits(v.w);
    ((v4s*)dst)[j] = p;
}

// C[m,n] = sum_k A[m,k] * Bt[n,k] + bias[n].  Tile: 128 x (NF*32), BK=32,
// double-buffered (stage k+1 right after the single per-iter barrier).
// XOR-4 swizzled 64B LDS rows - conflict-free. Output: cols >= 2048 scatter
// to Vt[bh][d][s] (measured-free vs coalesced store: r5/r6 + r8/r9 A/B);
// else store at ldc stride: Cf (fp32) if non-null, else C (bf16).
template<int NF>
__global__ __launch_bounds__(256)
void gemm_bt(const bf16* __restrict__ A, const bf16* __restrict__ Bt,
             const float* __restrict__ bias, bf16* __restrict__ C,
             float* __restrict__ Cf, bf16* __restrict__ Vt,
             int K, int lda, int ldc)
{
    constexpr int BN = NF * 32;
    __shared__ __align__(16) bf16 As[2][128 * 32];
    __shared__ __align__(16) bf16 Bs[2][BN * 32];

    const int t    = threadIdx.x;
    const int lane = t & 63;
    const int wave = t >> 6;
    const int l16  = lane & 15;
    const int quad = lane >> 4;
    const int m0   = blockIdx.y * 128;
    const int n0   = blockIdx.x * BN;
    const int wm   = (wave >> 1) * 64;        // 2x2 wave grid
    const int wn   = (wave & 1) * (NF * 16);

    const v4f zf = {0.f, 0.f, 0.f, 0.f};
    v4f acc[4][NF];
#pragma unroll
    for (int i = 0; i < 4; ++i)
#pragma unroll
        for (int j = 0; j < NF; ++j) acc[i][j] = zf;

    const int sr = t >> 2;
    const int g  = ((t & 3) ^ ((sr >> 1) & 3)) * 8;
    const bf16* gA = A  + (size_t)(m0 + sr) * lda + g;
    const bf16* gB = Bt + (size_t)(n0 + sr) * K + g;

    auto stage = [&](int kt, int buf) {
        const int k0 = kt * 32;
        char* lA = (char*)&As[buf][0] + t * 16;
        char* lB = (char*)&Bs[buf][0] + t * 16;
        __builtin_amdgcn_global_load_lds(AS1(gA + k0),                    AS3(lA),        16, 0, 0);
        __builtin_amdgcn_global_load_lds(AS1(gA + (size_t)64 * lda + k0), AS3(lA + 4096), 16, 0, 0);
        __builtin_amdgcn_global_load_lds(AS1(gB + k0),                    AS3(lB),        16, 0, 0);
        if (NF == 4)
            __builtin_amdgcn_global_load_lds(AS1(gB + (size_t)64 * K + k0), AS3(lB + 4096), 16, 0, 0);
    };

    stage(0, 0);
    const int KT = K >> 5;
    const int xs = ((l16 >> 1) & 3) * 8;   // read-side chunk swizzle
    for (int kt = 0; kt < KT; ++kt) {
        const int buf = kt & 1;
        __syncthreads();                    // buf staged; prev reads of buf^1 done
        if (kt + 1 < KT) stage(kt + 1, buf ^ 1);

        v8s af[4], bfr[NF];
#pragma unroll
        for (int mi = 0; mi < 4; ++mi)
            af[mi] = *(const v8s*)(&As[buf][0] + (wm + mi * 16 + l16) * 32
                                   + ((quad * 8) ^ xs));
#pragma unroll
        for (int ni = 0; ni < NF; ++ni)
            bfr[ni] = *(const v8s*)(&Bs[buf][0] + (wn + ni * 16 + l16) * 32
                                    + ((quad * 8) ^ xs));
#pragma unroll
        for (int mi = 0; mi < 4; ++mi)
#pragma unroll
            for (int ni = 0; ni < NF; ++ni)
                acc[mi][ni] = mfma_bf16(af[mi], bfr[ni], acc[mi][ni]);
    }

    // epilogue: D[row=quad*4+r][col=l16] per 16x16 tile (m91-verified layout)
#pragma unroll
    for (int ni = 0; ni < NF; ++ni) {
        const int col = n0 + wn + ni * 16 + l16;
        const float bv = bias[col];
#pragma unroll
        for (int mi = 0; mi < 4; ++mi) {
#pragma unroll
            for (int r = 0; r < 4; ++r) {
                const int row = m0 + wm + mi * 16 + quad * 4 + r;
                const float fv = acc[mi][ni][r] + bv;
                if (Vt && col >= 2048) {          // V third -> Vt[bh][d][s]
                    const int e = col - 2048;
                    const int hh = e >> 6, d = e & 63;
                    const int bb = row >> 11, s = row & 2047;
                    Vt[((((size_t)(bb * 16 + hh)) * 64 + d) << 11) + s] = __float2bfloat16(fv);
                } else if (Cf) {
                    Cf[(size_t)row * ldc + col] = fv;
                } else {
                    C[(size_t)row * ldc + col] = __float2bfloat16(fv);
                }
            }
        }
    }
}

// Block-cooperative causal flash attention, 64 q-rows/block (16/wave).
// qkv: [4096][2048] (Q cols 0..1023, K cols 1024..2047). Vt: [32*64][2048].
// att out: dense [4096][1024]. K AND V tiles (64) double-buffered in LDS via
// cooperative global_load_lds prefetch (r9 lesson: direct-VGPR scattered V
// loads are latency-death; cooperative staging is the hiding mechanism).
// ONE __syncthreads per tile. XOR-8 swizzled 128B LDS rows.
// Static-max softmax p = exp(s/8 - 14): no per-tile reductions/rescale.
#define M_STATIC 14.0f
__global__ __launch_bounds__(256)
void attn(const bf16* __restrict__ qkv, const bf16* __restrict__ Vt,
          bf16* __restrict__ att)
{
    __shared__ __align__(16) bf16 Ks[2][64 * 64];   // [krow][d-chunk swizzled]
    __shared__ __align__(16) bf16 Vs[2][64 * 64];   // [d][s-chunk swizzled]
    __shared__ __align__(16) short Ps[4][16 * 72];  // per-wave P, stride 72 (pad)

    const int t    = threadIdx.x;
    const int lane = t & 63;
    const int w    = t >> 6;
    const int l16  = lane & 15;
    const int quad = lane >> 4;
    const int id   = blockIdx.x;          // 1024 blocks
    const int bh   = id & 31;
    const int qb   = 31 - (id >> 5);      // heavy-first: qb 31..0
    const int b = bh >> 4, h = bh & 15;
    const int T = qb + 1;                 // 64-wide k-tiles to the causal frontier
    const int rowq = qb * 64 + w * 16;    // wave's first q-row

    // Q fragments (A-layout), 16 rows per wave
    v8s qf[2];
    {
        const bf16* Qb = qkv + (size_t)(b * 2048 + rowq + l16) * 2048 + h * 64 + quad * 8;
        qf[0] = *(const v8s*)(Qb);
        qf[1] = *(const v8s*)(Qb + 32);
    }

    // staging: thread t fetches 16B; LDS dst = t*16; global chunk = sc ^ (sr&7)
    const int sr  = t >> 3;          // row 0..31 within half-tile
    const int swz = ((t & 7) ^ (sr & 7)) * 8;
    const bf16* kbase = qkv + (size_t)(b * 2048 + sr) * 2048 + 1024 + h * 64 + swz;
    const bf16* vbase = Vt + (size_t)(bh * 64 + sr) * 2048 + swz;
    char* kd = (char*)&Ks[0][0] + t * 16;
    char* vd = (char*)&Vs[0][0] + t * 16;

    // stage tile 0 into buf 0
    __builtin_amdgcn_global_load_lds(AS1(kbase),                     AS3(kd),        16, 0, 0);
    __builtin_amdgcn_global_load_lds(AS1(kbase + (size_t)32 * 2048), AS3(kd + 4096), 16, 0, 0);
    __builtin_amdgcn_global_load_lds(AS1(vbase),                     AS3(vd),        16, 0, 0);
    __builtin_amdgcn_global_load_lds(AS1(vbase + (size_t)32 * 2048), AS3(vd + 4096), 16, 0, 0);

    const v4f zf = {0.f, 0.f, 0.f, 0.f};
    v4f o[4] = {zf, zf, zf, zf};
    float lsum[4] = {0.f, 0.f, 0.f, 0.f};
    short* Pw = &Ps[w][0];
    const int xsw = (l16 & 7) * 8;   // fragment-read swizzle (chunk' = c ^ (l16&7))

    for (int tile = 0; tile < T; ++tile) {
        const int buf = tile & 1;
        __syncthreads();   // staging of `tile` complete; all prior reads done
        if (tile + 1 < T) {          // prefetch next tile (drained at next barrier)
            const int nb = buf ^ 1;
            const bf16* ksrc = kbase + (size_t)((tile + 1) * 64) * 2048;
            const bf16* vsrc = vbase + (tile + 1) * 64;
            char* kdn = (char*)&Ks[nb][0] + t * 16;
            char* vdn = (char*)&Vs[nb][0] + t * 16;
            __builtin_amdgcn_global_load_lds(AS1(ksrc),                     AS3(kdn),        16, 0, 0);
            __builtin_amdgcn_global_load_lds(AS1(ksrc + (size_t)32 * 2048), AS3(kdn + 4096), 16, 0, 0);
            __builtin_amdgcn_global_load_lds(AS1(vsrc),                     AS3(vdn),        16, 0, 0);
            __builtin_amdgcn_global_load_lds(AS1(vsrc + (size_t)32 * 2048), AS3(vdn + 4096), 16, 0, 0);
        }

        // QK^T: S[16 rows][64 cols]
        v4f s[4] = {zf, zf, zf, zf};
#pragma unroll
        for (int ks = 0; ks < 2; ++ks)
#pragma unroll
            for (int ct = 0; ct < 4; ++ct) {
                const v8s kf = *(const v8s*)(&Ks[buf][0] + (ct * 16 + l16) * 64
                                             + (((ks * 4 + quad) * 8) ^ xsw));
                s[ct] = mfma_bf16(qf[ks], kf, s[ct]);
            }

        // exp (static max); mask only on the diagonal tile (wave-uniform branch)
        if (tile == T - 1) {
            const int colb = tile * 64;
            const int rowb = rowq + quad * 4;
#pragma unroll
            for (int ct = 0; ct < 4; ++ct) {
                const int col = colb + ct * 16 + l16;
#pragma unroll
                for (int r = 0; r < 4; ++r) {
                    const float p = (col > rowb + r)
                        ? 0.f : __expf(fmaf(s[ct][r], 0.125f, -M_STATIC));
                    lsum[r] += p;
                    Pw[(quad * 4 + r) * 72 + ct * 16 + l16] = bf16_bits(p);
                }
            }
        } else {
#pragma unroll
            for (int ct = 0; ct < 4; ++ct)
#pragma unroll
                for (int r = 0; r < 4; ++r) {
                    const float p = __expf(fmaf(s[ct][r], 0.125f, -M_STATIC));
                    lsum[r] += p;
                    Pw[(quad * 4 + r) * 72 + ct * 16 + l16] = bf16_bits(p);
                }
        }
        // per-wave P write->read ordering WITHOUT draining vmcnt (prefetch lives)
        asm volatile("s_waitcnt lgkmcnt(0)" ::: "memory");

        // PV: O += P[16x64] * V[64x64]
#pragma unroll
        for (int ks = 0; ks < 2; ++ks) {
            const v8s pf = *(const v8s*)(Pw + l16 * 72 + ks * 32 + quad * 8);
#pragma unroll
            for (int nt = 0; nt < 4; ++nt) {
                const v8s vf = *(const v8s*)(&Vs[buf][0] + (nt * 16 + l16) * 64
                                             + (((ks * 4 + quad) * 8) ^ xsw));
                o[nt] = mfma_bf16(pf, vf, o[nt]);
            }
        }
    }

    // row-sum: reduce partials across the 16 lanes holding each row (once)
#pragma unroll
    for (int r = 0; r < 4; ++r) {
        float l = lsum[r];
        l += __shfl_xor(l, 1); l += __shfl_xor(l, 2);
        l += __shfl_xor(l, 4); l += __shfl_xor(l, 8);
        lsum[r] = fmaxf(l, 1e-30f);
    }

    // dense attention output [4096][1024]
#pragma unroll
    for (int nt = 0; nt < 4; ++nt)
#pragma unroll
        for (int r = 0; r < 4; ++r) {
            const int row = rowq + quad * 4 + r;
            att[(size_t)(b * 2048 + row) * 1024 + h * 64 + nt * 16 + l16] =
                __float2bfloat16(o[nt][r] / lsum[r]);
        }
}

extern "C" void kernel_launch(void* const* d_in, const int* in_sizes, int n_in,
                              void* d_out, int out_size, void* d_ws, size_t ws_size,
                              hipStream_t stream)
{
    (void)in_sizes; (void)n_in; (void)out_size; (void)ws_size;
    const float* x     = (const float*)d_in[0];
    const float* w_in  = (const float*)d_in[1];
    const float* b_in  = (const float*)d_in[2];
    const float* w_out = (const float*)d_in[3];
    const float* b_out = (const float*)d_in[4];
    float* out = (float*)d_out;   // fp32 output [4096][1024]

    bf16* ws     = (bf16*)d_ws;
    bf16* xb     = ws;                           // [4096][1024]   8.4 MB
    bf16* w_inb  = xb     + (size_t)4096 * 1024; // [3072][1024]   6.3 MB
    bf16* w_outb = w_inb  + (size_t)3072 * 1024; // [1024][1024]   2.1 MB
    bf16* qkv    = w_outb + (size_t)1024 * 1024; // [4096][2048]  16.8 MB (Q,K)
    bf16* att    = qkv    + (size_t)4096 * 2048; // [4096][1024]   8.4 MB
    bf16* vt     = (bf16*)d_out;                 // [32*64][2048] scratch in d_out
                                                 // (dead before final GEMM writes out)

    cvt_all<<<8192, 256, 0, stream>>>(x, w_in, w_out, xb, w_inb, w_outb);

    // QKV projection: Q,K -> qkv (stride 2048); V scattered direct to Vt
    gemm_bt<4><<<dim3(24, 32), dim3(256), 0, stream>>>(xb, w_inb, b_in, qkv, nullptr,
                                                       vt, 1024, 1024, 2048);
    // causal flash attention -> dense att
    attn<<<1024, 256, 0, stream>>>(qkv, vt, att);
    // output projection -> fp32 d_out
    gemm_bt<2><<<dim3(16, 32), dim3(256), 0, stream>>>(att, w_outb, b_out, nullptr,
                                                       out, nullptr, 1024, 1024, 1024);
}